// Round 2
// baseline (1688.924 us; speedup 1.0000x reference)
//
#include <hip/hip_runtime.h>
#include <math.h>

#define NATOM 10000
#define NEDGE 320000
#define HDIM  128
#define NHEAD 8

__device__ __forceinline__ float silu_f(float x) {
    return x / (1.0f + expf(-x));
}

// ---------------------------------------------------------------- zero (float4)
__global__ __launch_bounds__(256) void k_zero4(float4* __restrict__ p, int n4) {
    int i = blockIdx.x * 256 + threadIdx.x;
    if (i < n4) p[i] = float4{0.f, 0.f, 0.f, 0.f};
}

// ---------------------------------------------------------------- q,k,v = x@W + b  (8 nodes/block)
__global__ __launch_bounds__(256) void k_node_qkv(
    const float* __restrict__ x,
    const float* __restrict__ Wq, const float* __restrict__ bq,
    const float* __restrict__ Wk, const float* __restrict__ bk,
    const float* __restrict__ Wv, const float* __restrict__ bv,
    float* __restrict__ q, float* __restrict__ k, float* __restrict__ v)
{
    __shared__ float xs[8 * HDIM];
    int base = blockIdx.x * 8;
    reinterpret_cast<float4*>(xs)[threadIdx.x] =
        reinterpret_cast<const float4*>(x + (size_t)base * HDIM)[threadIdx.x];
    __syncthreads();
    int h = threadIdx.x & 127, half = threadIdx.x >> 7;
    float aq[4], ak[4], av[4];
#pragma unroll
    for (int i = 0; i < 4; ++i) { aq[i] = bq[h]; ak[i] = bk[h]; av[i] = bv[h]; }
    for (int kk = 0; kk < HDIM; ++kk) {
        float wq = Wq[kk * HDIM + h], wk = Wk[kk * HDIM + h], wv = Wv[kk * HDIM + h];
#pragma unroll
        for (int i = 0; i < 4; ++i) {
            float xv = xs[(half + 2 * i) * HDIM + kk];
            aq[i] = fmaf(xv, wq, aq[i]);
            ak[i] = fmaf(xv, wk, ak[i]);
            av[i] = fmaf(xv, wv, av[i]);
        }
    }
#pragma unroll
    for (int i = 0; i < 4; ++i) {
        int node = base + half + 2 * i;
        q[(size_t)node * HDIM + h] = aq[i];
        k[(size_t)node * HDIM + h] = ak[i];
        v[(size_t)node * HDIM + h] = av[i];
    }
}

// ---------------------------------------------------------------- vec-side node GEMMs
__global__ __launch_bounds__(256) void k_node_vec(
    const float* __restrict__ vec,
    const float* __restrict__ Wvec,
    const float* __restrict__ Wwtrg, const float* __restrict__ Wwsrc,
    const float* __restrict__ Wttrg, const float* __restrict__ Wtsrc,
    float* __restrict__ vecdot, float* __restrict__ vec3o,
    float* __restrict__ vwt, float* __restrict__ vws,
    float* __restrict__ vtt, float* __restrict__ vts)
{
    __shared__ float vs[8 * 3 * HDIM];
    int base = blockIdx.x * 8;
    {
        const float4* vg = reinterpret_cast<const float4*>(vec + (size_t)base * 3 * HDIM);
        float4* vs4 = reinterpret_cast<float4*>(vs);
        for (int t = threadIdx.x; t < 768; t += 256) vs4[t] = vg[t];
    }
    __syncthreads();
    int h = threadIdx.x & 127, half = threadIdx.x >> 7;
    float vdot[4] = {0.f, 0.f, 0.f, 0.f};
    for (int s = 0; s < 3; ++s) {
        float a1[4] = {0,0,0,0}, a2[4] = {0,0,0,0}, a3[4] = {0,0,0,0};
        float awt[4] = {0,0,0,0}, aws[4] = {0,0,0,0}, att[4] = {0,0,0,0}, ats[4] = {0,0,0,0};
        for (int kk = 0; kk < HDIM; ++kk) {
            float w1 = Wvec[kk * 384 + h];
            float w2 = Wvec[kk * 384 + HDIM + h];
            float w3 = Wvec[kk * 384 + 2 * HDIM + h];
            float wwt = Wwtrg[kk * HDIM + h];
            float wws = Wwsrc[kk * HDIM + h];
            float wtt = Wttrg[kk * HDIM + h];
            float wts = Wtsrc[kk * HDIM + h];
#pragma unroll
            for (int i = 0; i < 4; ++i) {
                float vv = vs[((half + 2 * i) * 3 + s) * HDIM + kk];
                a1[i]  = fmaf(vv, w1, a1[i]);
                a2[i]  = fmaf(vv, w2, a2[i]);
                a3[i]  = fmaf(vv, w3, a3[i]);
                awt[i] = fmaf(vv, wwt, awt[i]);
                aws[i] = fmaf(vv, wws, aws[i]);
                att[i] = fmaf(vv, wtt, att[i]);
                ats[i] = fmaf(vv, wts, ats[i]);
            }
        }
#pragma unroll
        for (int i = 0; i < 4; ++i) {
            int node = base + half + 2 * i;
            size_t ob = ((size_t)node * 3 + s) * HDIM + h;
            vdot[i] += a1[i] * a2[i];
            vec3o[ob] = a3[i];
            vwt[ob] = awt[i];
            vws[ob] = aws[i];
            vtt[ob] = att[i];
            vts[ob] = ats[i];
        }
    }
#pragma unroll
    for (int i = 0; i < 4; ++i)
        vecdot[(size_t)(base + half + 2 * i) * HDIM + h] = vdot[i];
}

// ---------------------------------------------------------------- fused edge message pipeline
// Per 64-edge block:
//   P1: [dk|dv] = silu(f_ij @ [Wdk|Wdv] + b)        (GEMM, dk/dv stay in regs)
//   P2: attn    = silu(sum q*k*dk per head)*cutoff  (in-register, shfl_xor reduce)
//   P3: vj      = v[src]*dv*attn  -> LDS; atomicAdd into xagg
//   P4: s1|s2   = silu(vj @ Ws + bs)                (GEMM from LDS vj)
//   P5: vec_msg scatter-add into dvec (vagg region of d_out)
__global__ __launch_bounds__(256) void k_edge_fused(
    const float* __restrict__ fij, const int* __restrict__ eidx,
    const float* __restrict__ rij, const float* __restrict__ dij,
    const float* __restrict__ q, const float* __restrict__ k, const float* __restrict__ v,
    const float* __restrict__ vec,
    const float* __restrict__ Wdk, const float* __restrict__ bdk,
    const float* __restrict__ Wdv, const float* __restrict__ bdv,
    const float* __restrict__ Ws, const float* __restrict__ bs,
    float* __restrict__ xagg, float* __restrict__ dvec)
{
    __shared__ float ldsA[16 * 256];     // P1: A chunks [64][32]; P4: Ws chunks [16][256]
    __shared__ float ldsW[32 * 256];     // P1: W chunks [32][256]; P3/P4: vj [64][128]
    __shared__ int   srcS[64], dstS[64];
    __shared__ float rcutS[64];
    __shared__ float dS[64][3];

    int e0 = blockIdx.x * 64;
    if (threadIdx.x < 64) {
        srcS[threadIdx.x] = eidx[e0 + threadIdx.x];
        dstS[threadIdx.x] = eidx[NEDGE + e0 + threadIdx.x];
        float r = rij[e0 + threadIdx.x];
        rcutS[threadIdx.x] = (r < 5.0f) ? 0.5f * (cosf(r * 0.6283185307179586f) + 1.0f) : 0.0f;
    }
    if (threadIdx.x < 192) ((float*)dS)[threadIdx.x] = dij[(size_t)e0 * 3 + threadIdx.x];

    int tx = threadIdx.x & 31, ty = threadIdx.x >> 5;
    float acc[8][8];
#pragma unroll
    for (int i = 0; i < 8; ++i)
#pragma unroll
        for (int j = 0; j < 8; ++j) acc[i][j] = 0.f;

    // ---- P1: GEMM  f_ij[64x128] @ [Wdk|Wdv][128x256], K-chunks of 32
    for (int kc = 0; kc < 4; ++kc) {
#pragma unroll
        for (int it = 0; it < 2; ++it) {
            int f4 = threadIdx.x + it * 256;      // 512 float4 = [64][32]
            int m = f4 >> 3, c4 = f4 & 7;
            reinterpret_cast<float4*>(ldsA)[f4] =
                *reinterpret_cast<const float4*>(&fij[(size_t)(e0 + m) * HDIM + kc * 32 + c4 * 4]);
        }
#pragma unroll
        for (int it = 0; it < 8; ++it) {
            int f4 = threadIdx.x + it * 256;      // 2048 float4 = [32][256]
            int kk = f4 >> 6, oc4 = f4 & 63;
            int o = oc4 * 4;
            const float* sp = (o < HDIM) ? &Wdk[(size_t)(kc * 32 + kk) * HDIM + o]
                                         : &Wdv[(size_t)(kc * 32 + kk) * HDIM + (o - HDIM)];
            reinterpret_cast<float4*>(ldsW)[f4] = *reinterpret_cast<const float4*>(sp);
        }
        __syncthreads();
#pragma unroll 4
        for (int kk = 0; kk < 32; ++kk) {
            float a[8], b[8];
#pragma unroll
            for (int i = 0; i < 8; ++i) a[i] = ldsA[(ty * 8 + i) * 32 + kk];
#pragma unroll
            for (int j = 0; j < 8; ++j) b[j] = ldsW[kk * 256 + tx + 32 * j];
#pragma unroll
            for (int i = 0; i < 8; ++i)
#pragma unroll
                for (int j = 0; j < 8; ++j) acc[i][j] = fmaf(a[i], b[j], acc[i][j]);
        }
        __syncthreads();
    }

    float bdk_r[4], bdv_r[4];
#pragma unroll
    for (int j = 0; j < 4; ++j) {
        int c = tx + 32 * j;
        bdk_r[j] = bdk[c];
        bdv_r[j] = bdv[c];
    }

    // ---- P2: attention, fully in-register.
    // col c = tx+32*j belongs to head c>>4; the 16 lanes of a head group are a
    // contiguous 16-lane span, so shfl_xor 1/2/4/8 reduces within the group.
    float attn[8][4];
#pragma unroll
    for (int i = 0; i < 8; ++i) {
        int m = ty * 8 + i;
        int sn = srcS[m], dn = dstS[m];
        float rc = rcutS[m];
#pragma unroll
        for (int j = 0; j < 4; ++j) {
            int c = tx + 32 * j;
            float dk = silu_f(acc[i][j] + bdk_r[j]);
            float p = q[(size_t)dn * HDIM + c] * k[(size_t)sn * HDIM + c] * dk;
            p += __shfl_xor(p, 1);
            p += __shfl_xor(p, 2);
            p += __shfl_xor(p, 4);
            p += __shfl_xor(p, 8);
            attn[i][j] = silu_f(p) * rc;
        }
    }

    // ---- P3: vj -> LDS (ldsW reused) + xagg atomics
#pragma unroll
    for (int i = 0; i < 8; ++i) {
        int m = ty * 8 + i;
        int sn = srcS[m], dn = dstS[m];
#pragma unroll
        for (int j = 0; j < 4; ++j) {
            int c = tx + 32 * j;
            float dv = silu_f(acc[i][j + 4] + bdv_r[j]);
            float val = v[(size_t)sn * HDIM + c] * dv * attn[i][j];
            ldsW[m * HDIM + c] = val;
            atomicAdd(&xagg[(size_t)dn * HDIM + c], val);
        }
    }
    __syncthreads();

    // ---- P4: GEMM  vj[64x128] @ Ws[128x256], K-chunks of 16 (staged in ldsA)
#pragma unroll
    for (int i = 0; i < 8; ++i)
#pragma unroll
        for (int j = 0; j < 8; ++j) acc[i][j] = 0.f;

    for (int kc = 0; kc < 8; ++kc) {
#pragma unroll
        for (int it = 0; it < 4; ++it) {
            int f4 = threadIdx.x + it * 256;      // 1024 float4 = [16][256]
            int kk = f4 >> 6, oc4 = f4 & 63;
            reinterpret_cast<float4*>(ldsA)[f4] =
                reinterpret_cast<const float4*>(Ws)[(size_t)(kc * 16 + kk) * 64 + oc4];
        }
        __syncthreads();
#pragma unroll 4
        for (int kk = 0; kk < 16; ++kk) {
            float a[8], b[8];
#pragma unroll
            for (int i = 0; i < 8; ++i) a[i] = ldsW[(ty * 8 + i) * HDIM + kc * 16 + kk];
#pragma unroll
            for (int j = 0; j < 8; ++j) b[j] = ldsA[kk * 256 + tx + 32 * j];
#pragma unroll
            for (int i = 0; i < 8; ++i)
#pragma unroll
                for (int j = 0; j < 8; ++j) acc[i][j] = fmaf(a[i], b[j], acc[i][j]);
        }
        __syncthreads();
    }

    // ---- P5: vec_msg scatter
    float bs1[4], bs2[4];
#pragma unroll
    for (int j = 0; j < 4; ++j) {
        int c = tx + 32 * j;
        bs1[j] = bs[c];
        bs2[j] = bs[HDIM + c];
    }
#pragma unroll
    for (int i = 0; i < 8; ++i) {
        int m = ty * 8 + i;
        int dn = dstS[m], sn = srcS[m];
        float d0 = dS[m][0], d1 = dS[m][1], d2 = dS[m][2];
#pragma unroll
        for (int j = 0; j < 4; ++j) {
            int c = tx + 32 * j;
            float s1 = silu_f(acc[i][j] + bs1[j]);
            float s2 = silu_f(acc[i][j + 4] + bs2[j]);
            size_t vb = (size_t)sn * 3 * HDIM + c;
            size_t ab = (size_t)dn * 3 * HDIM + c;
            atomicAdd(&dvec[ab],            fmaf(vec[vb],            s1, s2 * d0));
            atomicAdd(&dvec[ab + HDIM],     fmaf(vec[vb + HDIM],     s1, s2 * d1));
            atomicAdd(&dvec[ab + 2 * HDIM], fmaf(vec[vb + 2 * HDIM], s1, s2 * d2));
        }
    }
}

// ---------------------------------------------------------------- node output: o=xagg@Wo+bo; dx, dvec+=vec3*o1
__global__ __launch_bounds__(256) void k_node_out(
    const float* __restrict__ xagg,
    const float* __restrict__ vecdot, const float* __restrict__ vec3o,
    const float* __restrict__ Wo, const float* __restrict__ bo,
    float* __restrict__ dx, float* __restrict__ dvec)
{
    __shared__ float xs[8 * HDIM];
    int base = blockIdx.x * 8;
    reinterpret_cast<float4*>(xs)[threadIdx.x] =
        reinterpret_cast<const float4*>(xagg + (size_t)base * HDIM)[threadIdx.x];
    __syncthreads();
    int h = threadIdx.x & 127, half = threadIdx.x >> 7;
    float o1[4], o2[4], o3[4];
#pragma unroll
    for (int i = 0; i < 4; ++i) { o1[i] = bo[h]; o2[i] = bo[HDIM + h]; o3[i] = bo[2 * HDIM + h]; }
    for (int kk = 0; kk < HDIM; ++kk) {
        float w1 = Wo[kk * 384 + h], w2 = Wo[kk * 384 + HDIM + h], w3 = Wo[kk * 384 + 2 * HDIM + h];
#pragma unroll
        for (int i = 0; i < 4; ++i) {
            float xv = xs[(half + 2 * i) * HDIM + kk];
            o1[i] = fmaf(xv, w1, o1[i]);
            o2[i] = fmaf(xv, w2, o2[i]);
            o3[i] = fmaf(xv, w3, o3[i]);
        }
    }
#pragma unroll
    for (int i = 0; i < 4; ++i) {
        int node = base + half + 2 * i;
        dx[(size_t)node * HDIM + h] = fmaf(vecdot[(size_t)node * HDIM + h], o2[i], o3[i]);
        size_t vb = (size_t)node * 3 * HDIM + h;
#pragma unroll
        for (int s = 0; s < 3; ++s)
            dvec[vb + s * HDIM] = fmaf(vec3o[vb + s * HDIM], o1[i], dvec[vb + s * HDIM]);
    }
}

// ---------------------------------------------------------------- fused f1/f2 GEMM + rejection dots + df
// wdot = a.b - (a.d)(b.d)  (d unit-norm; sign of d irrelevant)
__global__ __launch_bounds__(256) void k_edge_df(
    const float* __restrict__ fij, const int* __restrict__ eidx,
    const float* __restrict__ dij,
    const float* __restrict__ Wf, const float* __restrict__ bf,
    const float* __restrict__ vwt, const float* __restrict__ vws,
    const float* __restrict__ vtt, const float* __restrict__ vts,
    float* __restrict__ dfo)
{
    __shared__ float ldsA[64 * HDIM];
    __shared__ float ldsW[16 * 256];
    __shared__ int   srcS[64], dstS[64];
    __shared__ float dS[64][3];

    int e0 = blockIdx.x * 64;
    if (threadIdx.x < 64) {
        srcS[threadIdx.x] = eidx[e0 + threadIdx.x];
        dstS[threadIdx.x] = eidx[NEDGE + e0 + threadIdx.x];
    }
    if (threadIdx.x < 192) ((float*)dS)[threadIdx.x] = dij[(size_t)e0 * 3 + threadIdx.x];
#pragma unroll
    for (int it = 0; it < 8; ++it) {
        int f4 = threadIdx.x + it * 256;
        reinterpret_cast<float4*>(ldsA)[f4] =
            reinterpret_cast<const float4*>(fij + (size_t)e0 * HDIM)[f4];
    }
    __syncthreads();

    int tx = threadIdx.x & 31, ty = threadIdx.x >> 5;
    float acc[8][8];
#pragma unroll
    for (int i = 0; i < 8; ++i)
#pragma unroll
        for (int j = 0; j < 8; ++j) acc[i][j] = 0.f;

    for (int kc = 0; kc < 8; ++kc) {
#pragma unroll
        for (int it = 0; it < 4; ++it) {
            int f4 = threadIdx.x + it * 256;
            int kk = f4 >> 6, oc4 = f4 & 63;
            reinterpret_cast<float4*>(ldsW)[f4] =
                reinterpret_cast<const float4*>(Wf)[(size_t)(kc * 16 + kk) * 64 + oc4];
        }
        __syncthreads();
#pragma unroll 4
        for (int kk = 0; kk < 16; ++kk) {
            float a[8], b[8];
#pragma unroll
            for (int i = 0; i < 8; ++i) a[i] = ldsA[(ty * 8 + i) * HDIM + kc * 16 + kk];
#pragma unroll
            for (int j = 0; j < 8; ++j) b[j] = ldsW[kk * 256 + tx + 32 * j];
#pragma unroll
            for (int i = 0; i < 8; ++i)
#pragma unroll
                for (int j = 0; j < 8; ++j) acc[i][j] = fmaf(a[i], b[j], acc[i][j]);
        }
        __syncthreads();
    }
    float bf1[4], bf2[4];
#pragma unroll
    for (int j = 0; j < 4; ++j) {
        int c = tx + 32 * j;
        bf1[j] = bf[c];
        bf2[j] = bf[HDIM + c];
    }
#pragma unroll
    for (int i = 0; i < 8; ++i) {
        int m = ty * 8 + i;
        int dn = dstS[m], sn = srcS[m];
        float d0 = dS[m][0], d1 = dS[m][1], d2 = dS[m][2];
#pragma unroll
        for (int j = 0; j < 4; ++j) {
            int c = tx + 32 * j;
            float f1 = silu_f(acc[i][j] + bf1[j]);
            float f2 = silu_f(acc[i][j + 4] + bf2[j]);
            size_t db = (size_t)dn * 3 * HDIM + c;
            size_t sb = (size_t)sn * 3 * HDIM + c;
            float a0 = vwt[db], a1 = vwt[db + HDIM], a2 = vwt[db + 2 * HDIM];
            float b0 = vws[sb], b1 = vws[sb + HDIM], b2 = vws[sb + 2 * HDIM];
            float t10 = vtt[db], t11 = vtt[db + HDIM], t12 = vtt[db + 2 * HDIM];
            float t20 = vts[db], t21 = vts[db + HDIM], t22 = vts[db + 2 * HDIM];
            float A  = a0 * d0 + a1 * d1 + a2 * d2;
            float B  = b0 * d0 + b1 * d1 + b2 * d2;
            float P1 = t10 * d0 + t11 * d1 + t12 * d2;
            float P2 = t20 * d0 + t21 * d1 + t22 * d2;
            float wdot = a0 * b0 + a1 * b1 + a2 * b2 - A * B;
            float tdot = t10 * t20 + t11 * t21 + t12 * t22 - P1 * P2;
            dfo[(size_t)(e0 + m) * HDIM + c] = f1 * wdot + f2 * tdot;
        }
    }
}

// ----------------------------------------------------------------
extern "C" void kernel_launch(void* const* d_in, const int* in_sizes, int n_in,
                              void* d_out, int out_size, void* d_ws, size_t ws_size,
                              hipStream_t stream)
{
    const float* x     = (const float*)d_in[0];
    const float* vec   = (const float*)d_in[1];
    const int*   eidx  = (const int*)d_in[2];
    const float* rij   = (const float*)d_in[3];
    const float* fij   = (const float*)d_in[4];
    const float* dij   = (const float*)d_in[5];
    const float* Wq    = (const float*)d_in[6];
    const float* bq    = (const float*)d_in[7];
    const float* Wk    = (const float*)d_in[8];
    const float* bk    = (const float*)d_in[9];
    const float* Wv    = (const float*)d_in[10];
    const float* bv    = (const float*)d_in[11];
    const float* Wdk   = (const float*)d_in[12];
    const float* bdk   = (const float*)d_in[13];
    const float* Wdv   = (const float*)d_in[14];
    const float* bdv   = (const float*)d_in[15];
    const float* Wvec  = (const float*)d_in[16];
    const float* Ws    = (const float*)d_in[17];
    const float* bs    = (const float*)d_in[18];
    const float* Wo    = (const float*)d_in[19];
    const float* bo    = (const float*)d_in[20];
    const float* Wf    = (const float*)d_in[21];
    const float* bf    = (const float*)d_in[22];
    const float* Wwsrc = (const float*)d_in[23];
    const float* Wwtrg = (const float*)d_in[24];
    const float* Wtsrc = (const float*)d_in[25];
    const float* Wttrg = (const float*)d_in[26];

    float* ws = (float*)d_ws;
    size_t o = 0;
    float* q      = ws + o; o += (size_t)NATOM * HDIM;
    float* kf     = ws + o; o += (size_t)NATOM * HDIM;
    float* vf     = ws + o; o += (size_t)NATOM * HDIM;
    float* vecdot = ws + o; o += (size_t)NATOM * HDIM;
    float* vec3o  = ws + o; o += (size_t)NATOM * 3 * HDIM;
    float* vwt    = ws + o; o += (size_t)NATOM * 3 * HDIM;
    float* vws_   = ws + o; o += (size_t)NATOM * 3 * HDIM;
    float* vtt    = ws + o; o += (size_t)NATOM * 3 * HDIM;
    float* vts    = ws + o; o += (size_t)NATOM * 3 * HDIM;
    float* xagg   = ws + o; o += (size_t)NATOM * HDIM;
    // total ws: 25.6M floats = 102.4 MB

    float* dx   = (float*)d_out;
    float* dvec = dx + (size_t)NATOM * HDIM;        // also the vec_agg accumulator
    float* dfo  = dvec + (size_t)NATOM * 3 * HDIM;

    // zero xagg and dvec (accumulators)
    hipLaunchKernelGGL(k_zero4, dim3((NATOM * HDIM / 4 + 255) / 256), dim3(256), 0, stream,
                       (float4*)xagg, NATOM * HDIM / 4);
    hipLaunchKernelGGL(k_zero4, dim3((NATOM * 3 * HDIM / 4 + 255) / 256), dim3(256), 0, stream,
                       (float4*)dvec, NATOM * 3 * HDIM / 4);
    hipLaunchKernelGGL(k_node_qkv, dim3(NATOM / 8), dim3(256), 0, stream,
                       x, Wq, bq, Wk, bk, Wv, bv, q, kf, vf);
    hipLaunchKernelGGL(k_node_vec, dim3(NATOM / 8), dim3(256), 0, stream,
                       vec, Wvec, Wwtrg, Wwsrc, Wttrg, Wtsrc,
                       vecdot, vec3o, vwt, vws_, vtt, vts);
    hipLaunchKernelGGL(k_edge_fused, dim3(NEDGE / 64), dim3(256), 0, stream,
                       fij, eidx, rij, dij, q, kf, vf, vec,
                       Wdk, bdk, Wdv, bdv, Ws, bs, xagg, dvec);
    hipLaunchKernelGGL(k_node_out, dim3(NATOM / 8), dim3(256), 0, stream,
                       xagg, vecdot, vec3o, Wo, bo, dx, dvec);
    hipLaunchKernelGGL(k_edge_df, dim3(NEDGE / 64), dim3(256), 0, stream,
                       fij, eidx, dij, Wf, bf, vwt, vws_, vtt, vts, dfo);
}